// Round 3
// baseline (16648.280 us; speedup 1.0000x reference)
//
#include <hip/hip_runtime.h>
#include <math.h>

typedef long long i64;

#define EPSF 1e-8f

// ---------------- path metadata ----------------
constexpr int NPATH = 15;
constexpr int PI_[NPATH] = {0,0,1,1,1,1,0,1,1,2,2,2,2,2,2};
constexpr int PF_[NPATH] = {0,1,0,1,1,1,2,2,2,2,2,2,0,1,1};
constexpr int PO_[NPATH] = {0,1,1,0,1,2,2,1,2,0,1,2,2,1,2};
constexpr int ISZ[NPATH] = {1,1,3,3,3,3,1,3,3,5,5,5,5,5,5};
constexpr int FSZ[NPATH] = {1,3,1,3,3,3,5,5,5,5,5,5,1,3,3};
constexpr int OSZ[NPATH] = {1,3,3,1,3,5,5,3,5,1,3,5,5,3,5};
constexpr int IBASE[NPATH] = {0,0,1,1,1,1,0,1,1,4,4,4,4,4,4};
constexpr int FBASE[NPATH] = {0,1,0,1,1,1,4,4,4,4,4,4,0,1,1};
constexpr int OBASE[NPATH] = {0,1,1,0,1,4,4,1,4,0,1,4,4,1,4};
constexpr int CGOFF[NPATH+1] = {0,1,10,19,28,55,100,125,170,245,270,345,470,495,540,615};
// packed G offsets (sizes OSZ*ISZ)
constexpr int GOFF[NPATH+1]  = {0,1,4,13,16,25,40,45,54,69,74,89,114,139,154,179};
// float4-padded G offsets
constexpr int GPOFF[NPATH+1] = {0,4,8,20,24,36,52,60,72,88,96,112,140,168,184,212};
constexpr int CGTOT = 615;
constexpr int GPTOT = 212;

// ---------------- CG init (device-side, mirrors reference _su2_cg/_q) ----------------
__device__ double dfact(int n){ double r=1.0; for(int i=2;i<=n;++i) r*=(double)i; return r; }

__device__ double su2cg(int j1,int m1,int j2,int m2,int j3,int m3){
  if (m1+m2 != m3) return 0.0;
  int vmin = max(max(-j1+j2+m3, -j1+m1), 0);
  int vmax = min(min(j2+j3+m1, j3-j1+j2), j3+m3);
  if (vmax < vmin) return 0.0;
  double c = sqrt((double)(2*j3+1) * dfact(j3+j1-j2)*dfact(j3-j1+j2)*dfact(j1+j2-j3)
                  * dfact(j3+m3)*dfact(j3-m3)
                  / (dfact(j1+j2+j3+1)*dfact(j1-m1)*dfact(j1+m1)*dfact(j2-m2)*dfact(j2+m2)));
  double s = 0.0;
  for (int v=vmin; v<=vmax; ++v){
    double t = dfact(j2+j3+m1-v)*dfact(j1-m1+v)
             / (dfact(v)*dfact(j3-j1+j2-v)*dfact(j3+m3-v)*dfact(j1-j2-m3+v));
    s += ((v+j2+m2)&1) ? -t : t;
  }
  return c*s;
}

__device__ void qmat_lds(int l, double* qr, double* qi){
  for (int e=0;e<25;e++){ qr[e]=0.0; qi[e]=0.0; }
  const double s2 = 0.70710678118654752440;
  for (int m=-l; m<0; ++m){
    qr[(l+m)*5 + (l-m)] = s2;
    qi[(l+m)*5 + (l+m)] = -s2;
  }
  qr[l*5+l] = 1.0;
  for (int m=1; m<=l; ++m){
    double sg = (m&1)? -1.0 : 1.0;
    qr[(l+m)*5 + (l+m)] = sg*s2;
    qi[(l+m)*5 + (l-m)] = sg*s2;
  }
  if (l==1){
    for (int e=0;e<25;e++){ double r=qr[e], m=qi[e]; qr[e]=m; qi[e]=-r; }
  } else if (l==2){
    for (int e=0;e<25;e++){ qr[e]=-qr[e]; qi[e]=-qi[e]; }
  }
}

__global__ void cg_init_kernel(float* __restrict__ cg){
  int p = blockIdx.x;
  int li = PI_[p], lf = PF_[p], lo = PO_[p];
  int isz = 2*li+1, fsz = 2*lf+1, osz = 2*lo+1;
  __shared__ double sC[125];
  __shared__ double qir[25],qii[25],qfr[25],qfi[25],qor[25],qoi[25];
  if (threadIdx.x==0){
    qmat_lds(li,qir,qii); qmat_lds(lf,qfr,qfi); qmat_lds(lo,qor,qoi);
  }
  int tot = isz*fsz*osz;
  for (int e=threadIdx.x; e<tot; e+=blockDim.x){
    int a = e/(fsz*osz); int r = e%(fsz*osz); int b = r/osz; int n = r%osz;
    sC[e] = su2cg(li, a-li, lf, b-lf, lo, n-lo);
  }
  __syncthreads();
  for (int e=threadIdx.x; e<tot; e+=blockDim.x){
    int mo = e/(isz*fsz); int r = e%(isz*fsz); int ji = r/fsz; int lff = r%fsz;
    double acc = 0.0;
    for (int a=0;a<isz;a++) for(int b=0;b<fsz;b++) for(int n=0;n<osz;n++){
      double s = sC[(a*fsz+b)*osz+n];
      if (s==0.0) continue;
      double r1=qir[a*5+ji],  m1=qii[a*5+ji];
      double r2=qfr[b*5+lff], m2=qfi[b*5+lff];
      double r3=qor[n*5+mo],  m3=-qoi[n*5+mo];
      double rr = r1*r2 - m1*m2;
      double mm = r1*m2 + m1*r2;
      acc += (rr*r3 - mm*m3)*s;
    }
    cg[CGOFF[p] + (mo*isz+ji)*fsz + lff] = (float)acc;
  }
}

// ---------------- helpers ----------------
__device__ __forceinline__ float sspf(float x){
  float sp = (x > 20.f) ? x : log1pf(__expf(x));
  return sp - 0.69314718055994531f;
}

// ---------------- layer-1 self-interaction (one-hot input) ----------------
__global__ void siA1_kernel(const int* __restrict__ types, const float* __restrict__ w,
                            const float* __restrict__ b, float* __restrict__ Vp, int N){
  int idx = blockIdx.x*blockDim.x + threadIdx.x;
  if (idx >= N*24) return;
  int n = idx/24, d = idx%24;
  float v = w[d*3 + types[n]] + b[d];
  float* row = Vp + (i64)idx*12;
  row[0] = v;
  #pragma unroll
  for (int m=1;m<12;m++) row[m]=0.f;
}

// =====================================================================
// Kernel A (layers 1,2): thread=(a,c), T=192, one k per iteration.
// Two-pass inner: rr[15] (h from LDS float4, w2 from global L1) then
// G-contraction (padded float4 G from LDS). 128-VGPR cap.
// =====================================================================

template<int RT, int T, int P>
__device__ __forceinline__ void gphaseA(int t, const float* __restrict__ sbuf,
                                        const float* __restrict__ sCG, float* __restrict__ sG){
  if constexpr (P < NPATH){
    constexpr int gsz = OSZ[P]*ISZ[P];
    constexpr int TOT = RT*gsz;
    for (int e=t; e<TOT; e+=T){
      int row = e/gsz;
      int rel = e - row*gsz;
      const float* Yr = &sbuf[row*24 + 12 + FBASE[P]];
      const float* cr = &sCG[CGOFF[P] + rel*FSZ[P]];
      float v = 0.f;
      #pragma unroll
      for (int f=0; f<FSZ[P]; ++f) v += cr[f]*Yr[f];
      sG[row*GPTOT + GPOFF[P] + rel] = v;
    }
    gphaseA<RT,T,P+1>(t,sbuf,sCG,sG);
  }
}

template<int C, int P>
__device__ __forceinline__ void rphaseA(const float* __restrict__ gw2, const float* __restrict__ sb2,
                                        int c, const float* __restrict__ sh_a, float* rr){
  if constexpr (P < NPATH){
    const float* w = &gw2[(P*C+c)*12];
    const float* h = &sh_a[P*12];
    float4 w0 = *reinterpret_cast<const float4*>(w);
    float4 w1 = *reinterpret_cast<const float4*>(w+4);
    float4 w2 = *reinterpret_cast<const float4*>(w+8);
    float4 h0 = *reinterpret_cast<const float4*>(h);
    float4 h1 = *reinterpret_cast<const float4*>(h+4);
    float4 h2 = *reinterpret_cast<const float4*>(h+8);
    rr[P] = sb2[P*C+c]
      + w0.x*h0.x + w0.y*h0.y + w0.z*h0.z + w0.w*h0.w
      + w1.x*h1.x + w1.y*h1.y + w1.z*h1.z + w1.w*h1.w
      + w2.x*h2.x + w2.y*h2.y + w2.z*h2.z + w2.w*h2.w;
    rphaseA<C,P+1>(gw2,sb2,c,sh_a,rr);
  }
}

template<int P>
__device__ __forceinline__ void cphaseA(const float* __restrict__ sG_a, const float* rr,
                                        const float* vg, float* acc){
  if constexpr (P < NPATH){
    constexpr int gsz = OSZ[P]*ISZ[P];
    constexpr int NV = (gsz+3)/4;
    float gbuf[NV*4];
    #pragma unroll
    for (int v=0; v<NV; ++v)
      *reinterpret_cast<float4*>(&gbuf[4*v]) = *reinterpret_cast<const float4*>(&sG_a[GPOFF[P]+4*v]);
    const float rrp = rr[P];
    #pragma unroll
    for (int om=0; om<OSZ[P]; ++om){
      float wv = 0.f;
      #pragma unroll
      for (int im=0; im<ISZ[P]; ++im) wv += gbuf[om*ISZ[P]+im]*vg[IBASE[P]+im];
      acc[OBASE[P]+om] += rrp*wv;
    }
    cphaseA<P+1>(sG_a, rr, vg, acc);
  }
}

template<int C, int A>
__global__ __launch_bounds__(192, 4) void convA_kernel(
    const float* __restrict__ Vp, const int* __restrict__ nei_idx, const float* __restrict__ nei_vec,
    const float* __restrict__ gw1, const float* __restrict__ gb1,
    const float* __restrict__ gw2, const float* __restrict__ gb2,
    const float* __restrict__ cg, float* __restrict__ O, int N)
{
  constexpr int T = 192;
  static_assert(A*C == T, "bad geometry");
  __shared__ float sCG[CGTOT];
  __shared__ float sb2[15*C];
  __shared__ float sh[A*180];
  __shared__ float sG[A*GPTOT];
  __shared__ float sRbfY[2][A*24];

  const int t = threadIdx.x;
  const int a = t/C, c = t%C;
  const i64 atom0 = (i64)blockIdx.x*A;

  for (int e=t; e<CGTOT; e+=T) sCG[e]=cg[e];
  for (int e=t; e<15*C; e+=T) sb2[e]=gb2[e];

  auto stage = [&](int kn){
    if (t < A){
      const float* vv = nei_vec + ((atom0+t)*32 + kn)*3;
      float x=vv[0], y=vv[1], z=vv[2];
      float r2 = fmaxf(x*x+y*y+z*z, EPSF);
      float d = sqrtf(r2), inv = 1.f/r2;
      float* o = &sRbfY[kn&1][t*24];
      #pragma unroll
      for (int j=0;j<12;++j){ float dd = d - 0.72727272727272727f*(float)j; o[j] = __expf(-dd*dd); }
      o[12]=1.f; o[13]=x; o[14]=y; o[15]=z;
      o[16]=x*y*inv; o[17]=y*z*inv;
      o[18]=(2.f*z*z - x*x - y*y)*(0.28867513459481287f*inv);
      o[19]=z*x*inv; o[20]=(x*x - y*y)*(0.5f*inv);
    }
  };

  stage(0);
  __syncthreads();

  float acc[9];
  #pragma unroll
  for (int m=0;m<9;++m) acc[m]=0.f;

  for (int k=0; k<32; ++k){
    const float* sbuf = sRbfY[k&1];
    // h = relu(W1.rbf + b1); w1/b1 from global (L1-resident, coalesced rows)
    for (int e=t; e<A*180; e+=T){
      int row = e/180, j0 = e - row*180;
      const float* rb = &sbuf[row*24];
      const float* w  = &gw1[j0*12];
      float4 wv0 = *reinterpret_cast<const float4*>(w);
      float4 wv1 = *reinterpret_cast<const float4*>(w+4);
      float4 wv2 = *reinterpret_cast<const float4*>(w+8);
      float v = gb1[j0]
        + wv0.x*rb[0] + wv0.y*rb[1] + wv0.z*rb[2]  + wv0.w*rb[3]
        + wv1.x*rb[4] + wv1.y*rb[5] + wv1.z*rb[6]  + wv1.w*rb[7]
        + wv2.x*rb[8] + wv2.y*rb[9] + wv2.z*rb[10] + wv2.w*rb[11];
      sh[e] = fmaxf(v, 0.f);
    }
    // G = CG.Y (padded layout)
    gphaseA<A,T,0>(t, sbuf, sCG, sG);
    __syncthreads();
    // inner
    {
      int nei = nei_idx[(atom0+a)*32 + k];
      const float* vr = Vp + ((i64)nei*C + c)*12;
      float vg[9];
      float4 v0 = *reinterpret_cast<const float4*>(vr);
      float4 v1 = *reinterpret_cast<const float4*>(vr+4);
      vg[0]=v0.x; vg[1]=v0.y; vg[2]=v0.z; vg[3]=v0.w;
      vg[4]=v1.x; vg[5]=v1.y; vg[6]=v1.z; vg[7]=v1.w;
      vg[8]=vr[8];
      float rr[NPATH];
      rphaseA<C,0>(gw2, sb2, c, &sh[a*180], rr);
      cphaseA<0>(&sG[a*GPTOT], rr, vg, acc);
      if (k+1 < 32) stage(k+1);
    }
    __syncthreads();
  }

  float* orow = O + ((atom0+a)*C + c)*12;
  *reinterpret_cast<float4*>(orow)   = make_float4(acc[0],acc[1],acc[2],acc[3]);
  *reinterpret_cast<float4*>(orow+4) = make_float4(acc[4],acc[5],acc[6],acc[7]);
  orow[8] = acc[8];
}

// =====================================================================
// Kernel B (layer 3, C=4): staged-r + h/G buffer reuse (unchanged from R2)
// =====================================================================

template<int AK, int T, int P>
__device__ __forceinline__ void gphaseB(int t, const float* __restrict__ sYl,
                                        const float* __restrict__ sCG, float* __restrict__ sGb){
  if constexpr (P < NPATH){
    constexpr int gsz = OSZ[P]*ISZ[P];
    constexpr int TOT = AK*gsz;
    for (int e=t; e<TOT; e+=T){
      int row = e/gsz;
      int rel = e - row*gsz;
      const float* Yr = &sYl[row*12 + FBASE[P]];
      const float* cr = &sCG[CGOFF[P] + rel*FSZ[P]];
      float v = 0.f;
      #pragma unroll
      for (int f=0; f<FSZ[P]; ++f) v += cr[f]*Yr[f];
      sGb[row*180 + GOFF[P] + rel] = v;
    }
    gphaseB<AK,T,P+1>(t,sYl,sCG,sGb);
  }
}

template<int C, int P>
__device__ __forceinline__ void innerB(const float* __restrict__ sr_ak, const float* __restrict__ g_ak,
                                       int c, const float* __restrict__ vg, float* acc){
  if constexpr (P < NPATH){
    float rr = sr_ak[P*C + c];
    const float* Gp = &g_ak[GOFF[P]];
    #pragma unroll
    for (int om=0; om<OSZ[P]; ++om){
      float wv = 0.f;
      #pragma unroll
      for (int im=0; im<ISZ[P]; ++im) wv += Gp[om*ISZ[P]+im]*vg[IBASE[P]+im];
      acc[OBASE[P]+om] += rr*wv;
    }
    innerB<C,P+1>(sr_ak,g_ak,c,vg,acc);
  }
}

template<int C, int A, int KS, int T>
__global__ __launch_bounds__(T) void convB_kernel(
    const float* __restrict__ Vp, const int* __restrict__ nei_idx, const float* __restrict__ nei_vec,
    const float* __restrict__ gw1, const float* __restrict__ gb1,
    const float* __restrict__ gw2, const float* __restrict__ gb2,
    const float* __restrict__ cg, float* __restrict__ O, int N)
{
  constexpr int AK = A*KS;
  static_assert(A*KS*C == T, "bad geometry");
  __shared__ float sw1[2160];
  __shared__ float sCG[CGTOT];
  __shared__ float sb1[180];
  __shared__ float sb2[15*C];
  __shared__ float srbf[AK*12];
  __shared__ float sYl[AK*12];
  __shared__ float sbuf1[AK*180];
  __shared__ float sr[AK*15*C];

  const int t = threadIdx.x;
  const int a   = t/(C*KS);
  const int rks = (t%(C*KS))/C;
  const int c   = t%C;
  const int ak  = a*KS + rks;
  const i64 atom0 = (i64)blockIdx.x*A;

  for (int e=t; e<2160; e+=T) sw1[e]=gw1[e];
  for (int e=t; e<CGTOT; e+=T) sCG[e]=cg[e];
  for (int e=t; e<180; e+=T) sb1[e]=gb1[e];
  for (int e=t; e<15*C; e+=T) sb2[e]=gb2[e];
  __syncthreads();

  float acc[9];
  #pragma unroll
  for (int m=0;m<9;++m) acc[m]=0.f;

  for (int kc=0; kc<32/KS; ++kc){
    for (int e=t; e<AK; e+=T){
      int aa = e/KS, kss = e - aa*KS;
      int k = kc*KS + kss;
      const float* vv = nei_vec + ((atom0+aa)*32 + k)*3;
      float x=vv[0], y=vv[1], z=vv[2];
      float r2 = fmaxf(x*x+y*y+z*z, EPSF);
      float d = sqrtf(r2), inv = 1.f/r2;
      float* Ye = &sYl[e*12];
      Ye[0]=1.f; Ye[1]=x; Ye[2]=y; Ye[3]=z;
      Ye[4]=x*y*inv; Ye[5]=y*z*inv;
      Ye[6]=(2.f*z*z - x*x - y*y)*(0.28867513459481287f*inv);
      Ye[7]=z*x*inv; Ye[8]=(x*x - y*y)*(0.5f*inv);
      float* Re = &srbf[e*12];
      #pragma unroll
      for (int j=0;j<12;++j){ float dd = d - 0.72727272727272727f*(float)j; Re[j] = __expf(-dd*dd); }
    }
    __syncthreads();
    for (int e=t; e<AK*180; e+=T){
      int row = e/180, j0 = e - row*180;
      const float* w  = &sw1[j0*12];
      const float* rb = &srbf[row*12];
      float v = sb1[j0];
      #pragma unroll
      for (int j=0;j<12;++j) v += w[j]*rb[j];
      sbuf1[e] = fmaxf(v, 0.f);
    }
    __syncthreads();
    for (int e=t; e<AK*15*C; e+=T){
      int ak2 = e/(15*C); int rem = e - ak2*(15*C); int p = rem/C; int cc = rem - p*C;
      const float* w  = &gw2[(p*C+cc)*12];
      const float* hh = &sbuf1[ak2*180 + p*12];
      float v = sb2[p*C+cc];
      #pragma unroll
      for (int j=0;j<12;++j) v += w[j]*hh[j];
      sr[e] = v;
    }
    __syncthreads();
    gphaseB<AK,T,0>(t, sYl, sCG, sbuf1);
    __syncthreads();
    {
      int k = kc*KS + rks;
      int nei = nei_idx[(atom0+a)*32 + k];
      const float* vr = Vp + ((i64)nei*C + c)*12;
      float vg[12];
      *reinterpret_cast<float4*>(&vg[0]) = *reinterpret_cast<const float4*>(vr);
      *reinterpret_cast<float4*>(&vg[4]) = *reinterpret_cast<const float4*>(vr+4);
      vg[8] = vr[8]; vg[9]=vg[10]=vg[11]=0.f;
      innerB<C,0>(&sr[ak*15*C], &sbuf1[ak*180], c, vg, acc);
    }
    __syncthreads();
  }

  i64 at = atom0 + a;
  if constexpr (KS==1){
    float* orow = O + ((i64)at*C + c)*12;
    #pragma unroll
    for (int m=0;m<9;++m) orow[m]=acc[m];
  } else {
    float* red = sbuf1;
    int slot = (a*C + c)*KS + rks;
    #pragma unroll
    for (int m=0;m<9;++m) red[slot*9+m]=acc[m];
    __syncthreads();
    if (rks==0){
      float* orow = O + ((i64)at*C + c)*12;
      #pragma unroll
      for (int m=0;m<9;++m){
        float s=0.f;
        #pragma unroll
        for (int q=0;q<KS;++q) s += red[((a*C+c)*KS+q)*9+m];
        orow[m]=s;
      }
    }
  }
}

// ---------------- per-atom norm + siB + per-channel global sums ----------------
template<int C>
__global__ __launch_bounds__(64) void normsiB_kernel(
    const float* __restrict__ O, const float* __restrict__ w, const float* __restrict__ b,
    float* __restrict__ Vb, float* __restrict__ gsum, int N)
{
  __shared__ float sW[C*C];
  __shared__ float sO[C*9];
  __shared__ float sg[2*C];
  const int t = threadIdx.x;
  for (int e=t; e<C*C; e+=64) sW[e]=w[e];
  for (int e=t; e<2*C; e+=64) sg[e]=0.f;
  __syncthreads();
  const int iters = (N + gridDim.x - 1)/gridDim.x;
  for (int it=0; it<iters; ++it){
    i64 at = (i64)blockIdx.x + (i64)it*gridDim.x;
    float p0=0.f,p1=0.f,p2=0.f;
    if (at<(i64)N){
      for (int e=t; e<C*9; e+=64){
        int cc=e/9, m=e-cc*9;
        float v = O[((i64)at*C+cc)*12+m];
        sO[e]=v;
        float vv=v*v;
        if (m==0) p0+=vv; else if (m<4) p1+=vv; else p2+=vv;
      }
    }
    #pragma unroll
    for (int off=1; off<64; off<<=1){
      p0 += __shfl_xor(p0, off);
      p1 += __shfl_xor(p1, off);
      p2 += __shfl_xor(p2, off);
    }
    float i0 = 1.f/sqrtf(fmaxf(p0, EPSF));
    float i1 = 1.f/sqrtf(fmaxf(p1, EPSF));
    float i2 = 1.f/sqrtf(fmaxf(p2, EPSF));
    __syncthreads();
    if (at<(i64)N){
      for (int e=t; e<C*9; e+=64){
        int d=e/9, m=e-d*9;
        float inv = (m==0)? i0 : (m<4)? i1 : i2;
        const float* wr = &sW[d*C];
        float s=0.f;
        #pragma unroll
        for (int cc=0; cc<C; ++cc) s += wr[cc]*sO[cc*9+m];
        float outv = s*inv + ((m==0)? b[d] : 0.f);
        Vb[((i64)at*C+d)*12+m]=outv;
        if (m>=1) atomicAdd(&sg[(m<4?0:1)*C + d], outv*outv);
      }
    }
    __syncthreads();
  }
  for (int e=t; e<2*C; e+=64) atomicAdd(&gsum[e], sg[e]);
}

// ---------------- fused nonlinearity + next-layer siA ----------------
template<int Ci, int Co>
__global__ __launch_bounds__(64) void siaNL_kernel(
    const float* __restrict__ Vb, const float* __restrict__ gsum, const float* __restrict__ nlb,
    const float* __restrict__ w, const float* __restrict__ b, float* __restrict__ Vp, int N)
{
  __shared__ float sW[Co*Ci];
  __shared__ float sIn[Ci*9];
  __shared__ float sT[2*Ci];
  const int t=threadIdx.x;
  for (int e=t; e<Co*Ci; e+=64) sW[e]=w[e];
  for (int e=t; e<2*Ci;  e+=64) sT[e] = sqrtf(gsum[e]) + nlb[e];
  __syncthreads();
  const int iters = (N + gridDim.x - 1)/gridDim.x;
  for (int it=0; it<iters; ++it){
    i64 at = (i64)blockIdx.x + (i64)it*gridDim.x;
    if (at<(i64)N){
      for (int e=t; e<Ci*9; e+=64){
        int cc=e/9, m=e-cc*9;
        float v = Vb[((i64)at*Ci+cc)*12+m];
        float x = (m==0)? sspf(v) : (m<4)? v*sT[cc] : v*sT[Ci+cc];
        sIn[e]=x;
      }
    }
    __syncthreads();
    if (at<(i64)N){
      for (int e=t; e<Co*9; e+=64){
        int d=e/9, m=e-d*9;
        const float* wr=&sW[d*Ci];
        float s = (m==0)? b[d] : 0.f;
        #pragma unroll
        for (int cc=0;cc<Ci;++cc) s += wr[cc]*sIn[cc*9+m];
        Vp[((i64)at*Co+d)*12+m]=s;
      }
    }
    __syncthreads();
  }
}

// ---------------- final readout ----------------
__global__ void final_reduce_kernel(const float* __restrict__ Vb, float* __restrict__ Eacc, int N){
  __shared__ float sE[4];
  const int t=threadIdx.x;
  if (t<4) sE[t]=0.f;
  __syncthreads();
  float a0=0.f,a1=0.f,a2=0.f,a3=0.f;
  for (i64 at = (i64)blockIdx.x*blockDim.x + t; at < (i64)N; at += (i64)gridDim.x*blockDim.x){
    const float* row = Vb + at*4*12;
    a0 += sspf(row[0]);  a1 += sspf(row[12]);
    a2 += sspf(row[24]); a3 += sspf(row[36]);
  }
  atomicAdd(&sE[0],a0); atomicAdd(&sE[1],a1);
  atomicAdd(&sE[2],a2); atomicAdd(&sE[3],a3);
  __syncthreads();
  if (t<4) atomicAdd(&Eacc[t], sE[t]);
}

__global__ void final_dense_kernel(const float* __restrict__ Eacc,
    const float* __restrict__ w1,const float* __restrict__ b1,
    const float* __restrict__ w2,const float* __restrict__ b2,
    const float* __restrict__ w3,const float* __restrict__ b3,
    float* __restrict__ out)
{
  __shared__ float sE1[4];
  __shared__ float sH[256];
  const int t=threadIdx.x;
  if (t<4){
    float v=b1[t];
    #pragma unroll
    for (int j=0;j<4;j++) v += w1[t*4+j]*Eacc[j];
    sE1[t] = (v>0.f)? v : expm1f(v);
  }
  __syncthreads();
  {
    float v=b2[t];
    #pragma unroll
    for (int j=0;j<4;j++) v += w2[t*4+j]*sE1[j];
    sH[t]=v;
  }
  __syncthreads();
  if (t==0){
    float s=b3[0];
    for (int j=0;j<256;j++) s += w3[j]*sH[j];
    out[0]=s;
  }
}

// ---------------- launcher ----------------
extern "C" void kernel_launch(void* const* d_in, const int* in_sizes, int n_in,
                              void* d_out, int out_size, void* d_ws, size_t ws_size,
                              hipStream_t stream)
{
  const int* atom_types = (const int*)d_in[0];
  const int* nei_idx    = (const int*)d_in[1];
  const float* nei_vec  = (const float*)d_in[2];
  const float* in_f[36];
  for (int i=0;i<36 && i<n_in;i++) in_f[i] = (const float*)d_in[i];
  const int N = in_sizes[0];

  const i64 bsz = (i64)N*24*12;
  const size_t needed = 8192 + (size_t)3*bsz*4;
  if (ws_size < needed) return;

  char* ws = (char*)d_ws;
  float* cg   = (float*)ws;
  float* accs = (float*)(ws + 4096);
  float* gs1 = accs; float* gs2 = accs+48; float* gs3 = accs+72; float* Eacc = accs+80;
  float* bufA = (float*)(ws + 8192);
  float* bufB = bufA + bsz;
  float* bufC = bufB + bsz;

  #define LP(l, j) in_f[3 + 9*(l) + (j)]
  hipMemsetAsync(accs, 0, 512, stream);
  cg_init_kernel<<<15, 64, 0, stream>>>(cg);

  // ---- layer 1 (C=24) ----
  siA1_kernel<<<(N*24+255)/256, 256, 0, stream>>>(atom_types, LP(0,0), LP(0,1), bufB, N);
  convA_kernel<24,8><<<N/8, 192, 0, stream>>>(bufB, nei_idx, nei_vec,
      LP(0,2),LP(0,3),LP(0,4),LP(0,5), cg, bufC, N);
  normsiB_kernel<24><<<2048,64,0,stream>>>(bufC, LP(0,6), LP(0,7), bufA, gs1, N);
  // ---- layer 2 (C=12) ----
  siaNL_kernel<24,12><<<2048,64,0,stream>>>(bufA, gs1, LP(0,8), LP(1,0), LP(1,1), bufB, N);
  convA_kernel<12,16><<<N/16, 192, 0, stream>>>(bufB, nei_idx, nei_vec,
      LP(1,2),LP(1,3),LP(1,4),LP(1,5), cg, bufC, N);
  normsiB_kernel<12><<<2048,64,0,stream>>>(bufC, LP(1,6), LP(1,7), bufA, gs2, N);
  // ---- layer 3 (C=4) ----
  siaNL_kernel<12,4><<<2048,64,0,stream>>>(bufA, gs2, LP(1,8), LP(2,0), LP(2,1), bufB, N);
  convB_kernel<4,16,2,128><<<N/16, 128, 0, stream>>>(bufB, nei_idx, nei_vec,
      LP(2,2),LP(2,3),LP(2,4),LP(2,5), cg, bufC, N);
  normsiB_kernel<4><<<2048,64,0,stream>>>(bufC, LP(2,6), LP(2,7), bufA, gs3, N);
  // ---- readout ----
  final_reduce_kernel<<<128,256,0,stream>>>(bufA, Eacc, N);
  final_dense_kernel<<<1,256,0,stream>>>(Eacc, in_f[30],in_f[31],in_f[32],in_f[33],in_f[34],in_f[35],
                                         (float*)d_out);
  #undef LP
}

// Round 4
// 2341.019 us; speedup vs baseline: 7.1116x; 7.1116x over previous
//
#include <hip/hip_runtime.h>
#include <math.h>

typedef long long i64;

#define EPSF 1e-8f

// ---------------- path metadata ----------------
constexpr int NPATH = 15;
constexpr int PI_[NPATH] = {0,0,1,1,1,1,0,1,1,2,2,2,2,2,2};
constexpr int PF_[NPATH] = {0,1,0,1,1,1,2,2,2,2,2,2,0,1,1};
constexpr int PO_[NPATH] = {0,1,1,0,1,2,2,1,2,0,1,2,2,1,2};
constexpr int ISZ[NPATH] = {1,1,3,3,3,3,1,3,3,5,5,5,5,5,5};
constexpr int FSZ[NPATH] = {1,3,1,3,3,3,5,5,5,5,5,5,1,3,3};
constexpr int OSZ[NPATH] = {1,3,3,1,3,5,5,3,5,1,3,5,5,3,5};
constexpr int IBASE[NPATH] = {0,0,1,1,1,1,0,1,1,4,4,4,4,4,4};
constexpr int FBASE[NPATH] = {0,1,0,1,1,1,4,4,4,4,4,4,0,1,1};
constexpr int OBASE[NPATH] = {0,1,1,0,1,4,4,1,4,0,1,4,4,1,4};
constexpr int CGOFF[NPATH+1] = {0,1,10,19,28,55,100,125,170,245,270,345,470,495,540,615};
// float4-padded per-(a,k) G offsets (each path's OSZ*ISZ block padded to mult of 4)
constexpr int GPOFF[NPATH+1] = {0,4,8,20,24,36,52,60,72,88,96,112,140,168,184,212};
constexpr int CGTOT = 615;
constexpr int GPTOT = 212;

// ---------------- CG init (device-side, mirrors reference _su2_cg/_q) ----------------
__device__ double dfact(int n){ double r=1.0; for(int i=2;i<=n;++i) r*=(double)i; return r; }

__device__ double su2cg(int j1,int m1,int j2,int m2,int j3,int m3){
  if (m1+m2 != m3) return 0.0;
  int vmin = max(max(-j1+j2+m3, -j1+m1), 0);
  int vmax = min(min(j2+j3+m1, j3-j1+j2), j3+m3);
  if (vmax < vmin) return 0.0;
  double c = sqrt((double)(2*j3+1) * dfact(j3+j1-j2)*dfact(j3-j1+j2)*dfact(j1+j2-j3)
                  * dfact(j3+m3)*dfact(j3-m3)
                  / (dfact(j1+j2+j3+1)*dfact(j1-m1)*dfact(j1+m1)*dfact(j2-m2)*dfact(j2+m2)));
  double s = 0.0;
  for (int v=vmin; v<=vmax; ++v){
    double t = dfact(j2+j3+m1-v)*dfact(j1-m1+v)
             / (dfact(v)*dfact(j3-j1+j2-v)*dfact(j3+m3-v)*dfact(j1-j2-m3+v));
    s += ((v+j2+m2)&1) ? -t : t;
  }
  return c*s;
}

__device__ void qmat_lds(int l, double* qr, double* qi){
  for (int e=0;e<25;e++){ qr[e]=0.0; qi[e]=0.0; }
  const double s2 = 0.70710678118654752440;
  for (int m=-l; m<0; ++m){
    qr[(l+m)*5 + (l-m)] = s2;
    qi[(l+m)*5 + (l+m)] = -s2;
  }
  qr[l*5+l] = 1.0;
  for (int m=1; m<=l; ++m){
    double sg = (m&1)? -1.0 : 1.0;
    qr[(l+m)*5 + (l+m)] = sg*s2;
    qi[(l+m)*5 + (l-m)] = sg*s2;
  }
  if (l==1){
    for (int e=0;e<25;e++){ double r=qr[e], m=qi[e]; qr[e]=m; qi[e]=-r; }
  } else if (l==2){
    for (int e=0;e<25;e++){ qr[e]=-qr[e]; qi[e]=-qi[e]; }
  }
}

__global__ void cg_init_kernel(float* __restrict__ cg){
  int p = blockIdx.x;
  int li = PI_[p], lf = PF_[p], lo = PO_[p];
  int isz = 2*li+1, fsz = 2*lf+1, osz = 2*lo+1;
  __shared__ double sC[125];
  __shared__ double qir[25],qii[25],qfr[25],qfi[25],qor[25],qoi[25];
  if (threadIdx.x==0){
    qmat_lds(li,qir,qii); qmat_lds(lf,qfr,qfi); qmat_lds(lo,qor,qoi);
  }
  int tot = isz*fsz*osz;
  for (int e=threadIdx.x; e<tot; e+=blockDim.x){
    int a = e/(fsz*osz); int r = e%(fsz*osz); int b = r/osz; int n = r%osz;
    sC[e] = su2cg(li, a-li, lf, b-lf, lo, n-lo);
  }
  __syncthreads();
  for (int e=threadIdx.x; e<tot; e+=blockDim.x){
    int mo = e/(isz*fsz); int r = e%(isz*fsz); int ji = r/fsz; int lff = r%fsz;
    double acc = 0.0;
    for (int a=0;a<isz;a++) for(int b=0;b<fsz;b++) for(int n=0;n<osz;n++){
      double s = sC[(a*fsz+b)*osz+n];
      if (s==0.0) continue;
      double r1=qir[a*5+ji],  m1=qii[a*5+ji];
      double r2=qfr[b*5+lff], m2=qfi[b*5+lff];
      double r3=qor[n*5+mo],  m3=-qoi[n*5+mo];
      double rr = r1*r2 - m1*m2;
      double mm = r1*m2 + m1*r2;
      acc += (rr*r3 - mm*m3)*s;
    }
    cg[CGOFF[p] + (mo*isz+ji)*fsz + lff] = (float)acc;
  }
}

// ---------------- helpers ----------------
__device__ __forceinline__ float sspf(float x){
  float sp = (x > 20.f) ? x : log1pf(__expf(x));
  return sp - 0.69314718055994531f;
}

// ---------------- layer-1 self-interaction (one-hot input) ----------------
__global__ void siA1_kernel(const int* __restrict__ types, const float* __restrict__ w,
                            const float* __restrict__ b, float* __restrict__ Vp, int N){
  int idx = blockIdx.x*blockDim.x + threadIdx.x;
  if (idx >= N*24) return;
  int n = idx/24, d = idx%24;
  float v = w[d*3 + types[n]] + b[d];
  float* row = Vp + (i64)idx*12;
  row[0] = v;
  #pragma unroll
  for (int m=1;m<12;m++) row[m]=0.f;
}

// =====================================================================
// Unified conv kernel. T=192. Per k iteration:
//   phase hG: h[(p,hd)-mapped threads, w1 rows via LDS b128] +
//             G[(rel,a)-mapped threads, per-path compile-time]
//   sync
//   stage(k+1) + inner[(a,c)-mapped: inline r (w2 LDS b128) + G-stream]
//   sync
// All weights/CG in LDS (bounded register pressure; no hoisting across
// barriers). No per-thread arrays beyond acc[9]/vg[9]/vgr[5].
// =====================================================================

// per-path G = CG.Y into padded-float4 layout
template<int A, int P>
__device__ __forceinline__ void gphase(int t, const float* __restrict__ sY,
                                       const float* __restrict__ sCG, float* __restrict__ sG){
  if constexpr (P < NPATH){
    constexpr int gsz = OSZ[P]*ISZ[P];
    for (int e=t; e<gsz*A; e+=192){
      int a = e % A, rel = e / A;
      const float* cr = &sCG[CGOFF[P] + rel*FSZ[P]];
      const float* Yr = &sY[a*12 + FBASE[P]];
      float v = 0.f;
      #pragma unroll
      for (int f=0; f<FSZ[P]; ++f) v += cr[f]*Yr[f];
      sG[a*GPTOT + GPOFF[P] + rel] = v;
    }
    gphase<A,P+1>(t,sY,sCG,sG);
  }
}

// G-stream: consume padded G via float4, 1 LDS read : 4 FMA, no arrays
template<int P, int V>
__device__ __forceinline__ void gstream(const float* __restrict__ sG_a,
                                        const float* vgr, float* acc){
  constexpr int gsz = OSZ[P]*ISZ[P];
  if constexpr (4*V < gsz){
    float4 g = *reinterpret_cast<const float4*>(&sG_a[GPOFF[P] + 4*V]);
    constexpr int e0 = 4*V;
    acc[OBASE[P] + (e0  )/ISZ[P]] += g.x * vgr[(e0  )%ISZ[P]];
    if constexpr (e0+1 < gsz) acc[OBASE[P] + (e0+1)/ISZ[P]] += g.y * vgr[(e0+1)%ISZ[P]];
    if constexpr (e0+2 < gsz) acc[OBASE[P] + (e0+2)/ISZ[P]] += g.z * vgr[(e0+2)%ISZ[P]];
    if constexpr (e0+3 < gsz) acc[OBASE[P] + (e0+3)/ISZ[P]] += g.w * vgr[(e0+3)%ISZ[P]];
    gstream<P,V+1>(sG_a,vgr,acc);
  }
}

// inner per-path: rr = b2 + w2.h (both LDS float4), vgr = rr*vg, stream G
template<int C, int P, int PEND>
__device__ __forceinline__ void ipath(const float* __restrict__ sw2, const float* __restrict__ sb2,
                                      int c, const float* __restrict__ sh_a,
                                      const float* __restrict__ sG_a,
                                      const float* vg, float* acc){
  if constexpr (P < PEND){
    const float* w = &sw2[(P*C+c)*12];
    const float* h = &sh_a[P*12];
    float4 w0 = *reinterpret_cast<const float4*>(w);
    float4 w1 = *reinterpret_cast<const float4*>(w+4);
    float4 w2v= *reinterpret_cast<const float4*>(w+8);
    float4 h0 = *reinterpret_cast<const float4*>(h);
    float4 h1 = *reinterpret_cast<const float4*>(h+4);
    float4 h2 = *reinterpret_cast<const float4*>(h+8);
    float rr = sb2[P*C+c]
      + w0.x*h0.x + w0.y*h0.y + w0.z*h0.z + w0.w*h0.w
      + w1.x*h1.x + w1.y*h1.y + w1.z*h1.z + w1.w*h1.w
      + w2v.x*h2.x + w2v.y*h2.y + w2v.z*h2.z + w2v.w*h2.w;
    float vgr[5];
    #pragma unroll
    for (int i=0; i<ISZ[P]; ++i) vgr[i] = rr * vg[IBASE[P]+i];
    gstream<P,0>(sG_a, vgr, acc);
    ipath<C,P+1,PEND>(sw2,sb2,c,sh_a,sG_a,vg,acc);
  }
}

template<int C, int A, int PG>
__global__ __launch_bounds__(192) void conv_kernel(
    const float* __restrict__ Vp, const int* __restrict__ nei_idx, const float* __restrict__ nei_vec,
    const float* __restrict__ gw1, const float* __restrict__ gb1,
    const float* __restrict__ gw2, const float* __restrict__ gb2,
    const float* __restrict__ cg, float* __restrict__ O, int N)
{
  constexpr int T = 192;
  constexpr int PSPLIT = 10;          // path split point when PG==2
  static_assert(PG*A*C == T, "bad geometry");
  __shared__ float sw1[2160];
  __shared__ float sb1[180];
  __shared__ float sw2[15*C*12];
  __shared__ float sb2[15*C];
  __shared__ float sCG[CGTOT];
  __shared__ float srbf[A*12];
  __shared__ float sY[A*12];
  __shared__ float sh[A*180];
  __shared__ float sG[A*GPTOT];

  const int t = threadIdx.x;
  const i64 atom0 = (i64)blockIdx.x * A;

  for (int e=t; e<2160;    e+=T) sw1[e]=gw1[e];
  for (int e=t; e<180;     e+=T) sb1[e]=gb1[e];
  for (int e=t; e<15*C*12; e+=T) sw2[e]=gw2[e];
  for (int e=t; e<15*C;    e+=T) sb2[e]=gb2[e];
  for (int e=t; e<CGTOT;   e+=T) sCG[e]=cg[e];

  // one thread per atom: rbf + Y for neighbor k
  auto stage = [&](int k){
    if (t < A){
      i64 at = atom0 + t; if (at >= (i64)N) at = N-1;
      const float* vv = nei_vec + (at*32 + k)*3;
      float x=vv[0], y=vv[1], z=vv[2];
      float r2 = fmaxf(x*x+y*y+z*z, EPSF);
      float d = sqrtf(r2), inv = 1.f/r2;
      float* Re = &srbf[t*12];
      #pragma unroll
      for (int j=0;j<12;++j){ float dd = d - 0.72727272727272727f*(float)j; Re[j] = __expf(-dd*dd); }
      float* Ye = &sY[t*12];
      Ye[0]=1.f; Ye[1]=x; Ye[2]=y; Ye[3]=z;
      Ye[4]=x*y*inv; Ye[5]=y*z*inv;
      Ye[6]=(2.f*z*z - x*x - y*y)*(0.28867513459481287f*inv);
      Ye[7]=z*x*inv; Ye[8]=(x*x - y*y)*(0.5f*inv);
    }
  };

  stage(0);
  __syncthreads();

  // inner mapping
  const int pg = (PG==2) ? (t/(A*C)) : 0;
  const int rem = (PG==2) ? (t%(A*C)) : t;
  const int a = rem / C;
  const int c = rem % C;

  float acc[9];
  #pragma unroll
  for (int m=0;m<9;++m) acc[m]=0.f;

  for (int k=0; k<32; ++k){
    // ---- h phase: threads (p,hd), w1 row 3x b128 from LDS ----
    if (t < 180){
      int p = t/12, hd = t%12;
      const float* w = &sw1[(p*12+hd)*12];
      float4 a0 = *reinterpret_cast<const float4*>(w);
      float4 a1 = *reinterpret_cast<const float4*>(w+4);
      float4 a2 = *reinterpret_cast<const float4*>(w+8);
      float bb = sb1[p*12+hd];
      for (int aa=0; aa<A; ++aa){
        const float* rb = &srbf[aa*12];
        float4 r0 = *reinterpret_cast<const float4*>(rb);
        float4 r1 = *reinterpret_cast<const float4*>(rb+4);
        float4 r2 = *reinterpret_cast<const float4*>(rb+8);
        float v = bb
          + a0.x*r0.x + a0.y*r0.y + a0.z*r0.z + a0.w*r0.w
          + a1.x*r1.x + a1.y*r1.y + a1.z*r1.z + a1.w*r1.w
          + a2.x*r2.x + a2.y*r2.y + a2.z*r2.z + a2.w*r2.w;
        sh[aa*180 + p*12 + hd] = fmaxf(v, 0.f);
      }
    }
    // ---- G phase: per-path compile-time, threads (rel,a) ----
    gphase<A,0>(t, sY, sCG, sG);
    __syncthreads();
    // ---- stage next k's rbf/Y (overlaps inner's global gather) ----
    if (k+1 < 32) stage(k+1);
    // ---- inner: inline r + G-stream per (a,c) ----
    {
      i64 at = atom0 + a; if (at >= (i64)N) at = N-1;
      int nei = nei_idx[at*32 + k];
      const float* vr = Vp + ((i64)nei*C + c)*12;
      float vg[9];
      float4 v0 = *reinterpret_cast<const float4*>(vr);
      float4 v1 = *reinterpret_cast<const float4*>(vr+4);
      vg[0]=v0.x; vg[1]=v0.y; vg[2]=v0.z; vg[3]=v0.w;
      vg[4]=v1.x; vg[5]=v1.y; vg[6]=v1.z; vg[7]=v1.w;
      vg[8]=vr[8];
      if constexpr (PG==1){
        ipath<C,0,NPATH>(sw2,sb2,c,&sh[a*180],&sG[a*GPTOT],vg,acc);
      } else {
        if (pg==0) ipath<C,0,PSPLIT>(sw2,sb2,c,&sh[a*180],&sG[a*GPTOT],vg,acc);
        else       ipath<C,PSPLIT,NPATH>(sw2,sb2,c,&sh[a*180],&sG[a*GPTOT],vg,acc);
      }
    }
    __syncthreads();
  }

  // ---- store (PG==2: combine path-group partials via LDS) ----
  i64 at = atom0 + a;
  if constexpr (PG==1){
    if (at < (i64)N){
      float* orow = O + (at*C + c)*12;
      *reinterpret_cast<float4*>(orow)   = make_float4(acc[0],acc[1],acc[2],acc[3]);
      *reinterpret_cast<float4*>(orow+4) = make_float4(acc[4],acc[5],acc[6],acc[7]);
      orow[8] = acc[8];
    }
  } else {
    if (pg==1){
      float* red = &sh[(a*C+c)*9];
      #pragma unroll
      for (int m=0;m<9;++m) red[m]=acc[m];
    }
    __syncthreads();
    if (pg==0 && at < (i64)N){
      const float* red = &sh[(a*C+c)*9];
      float* orow = O + (at*C + c)*12;
      #pragma unroll
      for (int m=0;m<9;++m) orow[m] = acc[m] + red[m];
    }
  }
}

// ---------------- per-atom norm + siB + per-channel global sums ----------------
template<int C>
__global__ __launch_bounds__(64) void normsiB_kernel(
    const float* __restrict__ O, const float* __restrict__ w, const float* __restrict__ b,
    float* __restrict__ Vb, float* __restrict__ gsum, int N)
{
  __shared__ float sW[C*C];
  __shared__ float sO[C*9];
  __shared__ float sg[2*C];
  const int t = threadIdx.x;
  for (int e=t; e<C*C; e+=64) sW[e]=w[e];
  for (int e=t; e<2*C; e+=64) sg[e]=0.f;
  __syncthreads();
  const int iters = (N + gridDim.x - 1)/gridDim.x;
  for (int it=0; it<iters; ++it){
    i64 at = (i64)blockIdx.x + (i64)it*gridDim.x;
    float p0=0.f,p1=0.f,p2=0.f;
    if (at<(i64)N){
      for (int e=t; e<C*9; e+=64){
        int cc=e/9, m=e-cc*9;
        float v = O[((i64)at*C+cc)*12+m];
        sO[e]=v;
        float vv=v*v;
        if (m==0) p0+=vv; else if (m<4) p1+=vv; else p2+=vv;
      }
    }
    #pragma unroll
    for (int off=1; off<64; off<<=1){
      p0 += __shfl_xor(p0, off);
      p1 += __shfl_xor(p1, off);
      p2 += __shfl_xor(p2, off);
    }
    float i0 = 1.f/sqrtf(fmaxf(p0, EPSF));
    float i1 = 1.f/sqrtf(fmaxf(p1, EPSF));
    float i2 = 1.f/sqrtf(fmaxf(p2, EPSF));
    __syncthreads();
    if (at<(i64)N){
      for (int e=t; e<C*9; e+=64){
        int d=e/9, m=e-d*9;
        float inv = (m==0)? i0 : (m<4)? i1 : i2;
        const float* wr = &sW[d*C];
        float s=0.f;
        #pragma unroll
        for (int cc=0; cc<C; ++cc) s += wr[cc]*sO[cc*9+m];
        float outv = s*inv + ((m==0)? b[d] : 0.f);
        Vb[((i64)at*C+d)*12+m]=outv;
        if (m>=1) atomicAdd(&sg[(m<4?0:1)*C + d], outv*outv);
      }
    }
    __syncthreads();
  }
  for (int e=t; e<2*C; e+=64) atomicAdd(&gsum[e], sg[e]);
}

// ---------------- fused nonlinearity + next-layer siA ----------------
template<int Ci, int Co>
__global__ __launch_bounds__(64) void siaNL_kernel(
    const float* __restrict__ Vb, const float* __restrict__ gsum, const float* __restrict__ nlb,
    const float* __restrict__ w, const float* __restrict__ b, float* __restrict__ Vp, int N)
{
  __shared__ float sW[Co*Ci];
  __shared__ float sIn[Ci*9];
  __shared__ float sT[2*Ci];
  const int t=threadIdx.x;
  for (int e=t; e<Co*Ci; e+=64) sW[e]=w[e];
  for (int e=t; e<2*Ci;  e+=64) sT[e] = sqrtf(gsum[e]) + nlb[e];
  __syncthreads();
  const int iters = (N + gridDim.x - 1)/gridDim.x;
  for (int it=0; it<iters; ++it){
    i64 at = (i64)blockIdx.x + (i64)it*gridDim.x;
    if (at<(i64)N){
      for (int e=t; e<Ci*9; e+=64){
        int cc=e/9, m=e-cc*9;
        float v = Vb[((i64)at*Ci+cc)*12+m];
        float x = (m==0)? sspf(v) : (m<4)? v*sT[cc] : v*sT[Ci+cc];
        sIn[e]=x;
      }
    }
    __syncthreads();
    if (at<(i64)N){
      for (int e=t; e<Co*9; e+=64){
        int d=e/9, m=e-d*9;
        const float* wr=&sW[d*Ci];
        float s = (m==0)? b[d] : 0.f;
        #pragma unroll
        for (int cc=0;cc<Ci;++cc) s += wr[cc]*sIn[cc*9+m];
        Vp[((i64)at*Co+d)*12+m]=s;
      }
    }
    __syncthreads();
  }
}

// ---------------- final readout ----------------
__global__ void final_reduce_kernel(const float* __restrict__ Vb, float* __restrict__ Eacc, int N){
  __shared__ float sE[4];
  const int t=threadIdx.x;
  if (t<4) sE[t]=0.f;
  __syncthreads();
  float a0=0.f,a1=0.f,a2=0.f,a3=0.f;
  for (i64 at = (i64)blockIdx.x*blockDim.x + t; at < (i64)N; at += (i64)gridDim.x*blockDim.x){
    const float* row = Vb + at*4*12;
    a0 += sspf(row[0]);  a1 += sspf(row[12]);
    a2 += sspf(row[24]); a3 += sspf(row[36]);
  }
  atomicAdd(&sE[0],a0); atomicAdd(&sE[1],a1);
  atomicAdd(&sE[2],a2); atomicAdd(&sE[3],a3);
  __syncthreads();
  if (t<4) atomicAdd(&Eacc[t], sE[t]);
}

__global__ void final_dense_kernel(const float* __restrict__ Eacc,
    const float* __restrict__ w1,const float* __restrict__ b1,
    const float* __restrict__ w2,const float* __restrict__ b2,
    const float* __restrict__ w3,const float* __restrict__ b3,
    float* __restrict__ out)
{
  __shared__ float sE1[4];
  __shared__ float sH[256];
  const int t=threadIdx.x;
  if (t<4){
    float v=b1[t];
    #pragma unroll
    for (int j=0;j<4;j++) v += w1[t*4+j]*Eacc[j];
    sE1[t] = (v>0.f)? v : expm1f(v);
  }
  __syncthreads();
  {
    float v=b2[t];
    #pragma unroll
    for (int j=0;j<4;j++) v += w2[t*4+j]*sE1[j];
    sH[t]=v;
  }
  __syncthreads();
  if (t==0){
    float s=b3[0];
    for (int j=0;j<256;j++) s += w3[j]*sH[j];
    out[0]=s;
  }
}

// ---------------- launcher ----------------
extern "C" void kernel_launch(void* const* d_in, const int* in_sizes, int n_in,
                              void* d_out, int out_size, void* d_ws, size_t ws_size,
                              hipStream_t stream)
{
  const int* atom_types = (const int*)d_in[0];
  const int* nei_idx    = (const int*)d_in[1];
  const float* nei_vec  = (const float*)d_in[2];
  const float* in_f[36];
  for (int i=0;i<36 && i<n_in;i++) in_f[i] = (const float*)d_in[i];
  const int N = in_sizes[0];

  const i64 bsz = (i64)N*24*12;
  const size_t needed = 8192 + (size_t)3*bsz*4;
  if (ws_size < needed) return;

  char* ws = (char*)d_ws;
  float* cg   = (float*)ws;
  float* accs = (float*)(ws + 4096);
  float* gs1 = accs; float* gs2 = accs+48; float* gs3 = accs+72; float* Eacc = accs+80;
  float* bufA = (float*)(ws + 8192);
  float* bufB = bufA + bsz;
  float* bufC = bufB + bsz;

  #define LP(l, j) in_f[3 + 9*(l) + (j)]
  hipMemsetAsync(accs, 0, 512, stream);
  cg_init_kernel<<<15, 64, 0, stream>>>(cg);

  // ---- layer 1 (C=24, A=8) ----
  siA1_kernel<<<(N*24+255)/256, 256, 0, stream>>>(atom_types, LP(0,0), LP(0,1), bufB, N);
  conv_kernel<24,8,1><<<(N+7)/8, 192, 0, stream>>>(bufB, nei_idx, nei_vec,
      LP(0,2),LP(0,3),LP(0,4),LP(0,5), cg, bufC, N);
  normsiB_kernel<24><<<2048,64,0,stream>>>(bufC, LP(0,6), LP(0,7), bufA, gs1, N);
  // ---- layer 2 (C=12, A=16) ----
  siaNL_kernel<24,12><<<2048,64,0,stream>>>(bufA, gs1, LP(0,8), LP(1,0), LP(1,1), bufB, N);
  conv_kernel<12,16,1><<<(N+15)/16, 192, 0, stream>>>(bufB, nei_idx, nei_vec,
      LP(1,2),LP(1,3),LP(1,4),LP(1,5), cg, bufC, N);
  normsiB_kernel<12><<<2048,64,0,stream>>>(bufC, LP(1,6), LP(1,7), bufA, gs2, N);
  // ---- layer 3 (C=4, A=24, 2-way path split) ----
  siaNL_kernel<12,4><<<2048,64,0,stream>>>(bufA, gs2, LP(1,8), LP(2,0), LP(2,1), bufB, N);
  conv_kernel<4,24,2><<<(N+23)/24, 192, 0, stream>>>(bufB, nei_idx, nei_vec,
      LP(2,2),LP(2,3),LP(2,4),LP(2,5), cg, bufC, N);
  normsiB_kernel<4><<<2048,64,0,stream>>>(bufC, LP(2,6), LP(2,7), bufA, gs3, N);
  // ---- readout ----
  final_reduce_kernel<<<128,256,0,stream>>>(bufA, Eacc, N);
  final_dense_kernel<<<1,256,0,stream>>>(Eacc, in_f[30],in_f[31],in_f[32],in_f[33],in_f[34],in_f[35],
                                         (float*)d_out);
  #undef LP
}